// Round 3
// baseline (267.560 us; speedup 1.0000x reference)
//
#include <hip/hip_runtime.h>

#define PI_D 3.14159265358979323846
#define PI_F 3.14159265358979323846f

// ---- workspace layout (floats) ----
// U01 @ 0        : 16*256*256 = 1048576
// U02 @ 1048576  : 1048576
// U12 @ 2097152  : 16*128*128 = 262144
// V01 @ 2359296  : 16*128*256 = 524288
// V02 @ 2883584  : 16*64*256  = 262144
// V12 @ 3145728  : 16*64*128  = 131072
// R01 @ 3276800  : 256
// R02 @ 3277056  : 256
// R12 @ 3277312  : 128
// P1  @ 3277440  : 16
// P2  @ 3277456  : 16     -> ~12.5 MB

__device__ inline float rtab_val(int n, int m2, int t) {
  if (t == 0) return 1.0f;
  double th = PI_D * (double)t / (double)n;
  double v = sin(th * (double)(m2 - 1)) / sin(th) + cos(th * (double)m2);
  return (float)(v / (double)m2);  // 1/m2 per axis
}

// block 0: R tables; blocks 1..16: P1 from X1; blocks 17..32: P2 from X2
__global__ __launch_bounds__(256) void k_prep(const float* __restrict__ X1,
                                              const float* __restrict__ X2,
                                              float* __restrict__ R01,
                                              float* __restrict__ R02,
                                              float* __restrict__ R12,
                                              float* __restrict__ P1,
                                              float* __restrict__ P2) {
  int bid = blockIdx.x;
  int t = threadIdx.x;
  if (bid == 0) {
    R01[t] = rtab_val(256, 128, t);
    R02[t] = rtab_val(256, 64, t);
    if (t < 128) R12[t] = rtab_val(128, 64, t);
    return;
  }
  const float* X; float* P; int lg, ch;
  if (bid <= 16) { X = X1; P = P1; lg = 7; ch = bid - 1; }
  else           { X = X2; P = P2; lg = 6; ch = bid - 17; }
  int n = 1 << lg;
  int total = n * n;
  const float* x = X + (size_t)ch * total;
  float s = 0.f;
  for (int idx = t; idx < total; idx += 256) {
    float v = x[idx];
    s += (((idx >> lg) ^ idx) & 1) ? -v : v;  // (-1)^(nx+ny)
  }
#pragma unroll
  for (int off = 32; off > 0; off >>= 1) s += __shfl_down(s, off, 64);
  __shared__ float red[4];
  if ((t & 63) == 0) red[t >> 6] = s;
  __syncthreads();
  if (t == 0) P[ch] = red[0] + red[1] + red[2] + red[3];
}

// Pass V: v[ch][nx][my] = sum_ny x2[ch][nx][ny] * R[(my - s*ny) mod n1]
// grid 256: [0,128) p01, [128,192) p02, [192,256) p12
__global__ __launch_bounds__(256) void k_V(const float* __restrict__ X1c,
                                           const float* __restrict__ X2c,
                                           const float* __restrict__ R01,
                                           const float* __restrict__ R02,
                                           const float* __restrict__ R12,
                                           float* __restrict__ V01,
                                           float* __restrict__ V02,
                                           float* __restrict__ V12) {
  int bid = blockIdx.x;
  const float* X; const float* Rt; float* V;
  int n1, n2, s, ch, nxg;
  if (bid < 128)      { X = X1c; Rt = R01; V = V01; n1 = 256; n2 = 128; s = 2; ch = bid >> 3; nxg = (bid & 7) * 16; }
  else if (bid < 192) { bid -= 128; X = X2c; Rt = R02; V = V02; n1 = 256; n2 = 64; s = 4; ch = bid >> 2; nxg = (bid & 3) * 16; }
  else                { bid -= 192; X = X2c; Rt = R12; V = V12; n1 = 128; n2 = 64; s = 2; ch = bid >> 2; nxg = (bid & 3) * 16; }
  __shared__ float Rl[256];
  __shared__ float Xs[16 * 128];
  int t = threadIdx.x;
  for (int i = t; i < n1; i += 256) Rl[i] = Rt[i];
  const float* xch = X + (size_t)ch * n2 * n2 + (size_t)nxg * n2;
  for (int i = t; i < 16 * n2; i += 256) Xs[i] = xch[i];
  __syncthreads();
  int myq = t & 63;
  int nxq = t >> 6;  // wave-uniform
  int nmy = n1 >> 6; // 4 or 2
  int mask = n1 - 1;
  float acc[4][4];
#pragma unroll
  for (int r = 0; r < 4; ++r)
#pragma unroll
    for (int c = 0; c < 4; ++c) acc[r][c] = 0.f;
  for (int ny = 0; ny < n2; ++ny) {
    float xv[4];
#pragma unroll
    for (int r = 0; r < 4; ++r) xv[r] = Xs[(4 * nxq + r) * n2 + ny];
#pragma unroll
    for (int c = 0; c < 4; ++c) {
      float rv = Rl[(myq + 64 * c - s * ny) & mask];
#pragma unroll
      for (int r = 0; r < 4; ++r) acc[r][c] += xv[r] * rv;
    }
  }
  float* vch = V + (size_t)ch * n2 * n1;
#pragma unroll
  for (int r = 0; r < 4; ++r)
    for (int c = 0; c < nmy; ++c)
      vch[(size_t)(nxg + 4 * nxq + r) * n1 + myq + 64 * c] = acc[r][c];
}

// Pass U: u[ch][mx][my] = sum_nx R[(mx - s*nx) mod n1] * v[ch][nx][my]
//                         - inv*sin(a*mx)*sin(a*my)*P[ch]
// grid 640: [0,256) p01, [256,512) p02, [512,640) p12
__global__ __launch_bounds__(256) void k_U(const float* __restrict__ V01,
                                           const float* __restrict__ V02,
                                           const float* __restrict__ V12,
                                           const float* __restrict__ R01,
                                           const float* __restrict__ R02,
                                           const float* __restrict__ R12,
                                           const float* __restrict__ P1,
                                           const float* __restrict__ P2,
                                           float* __restrict__ U01,
                                           float* __restrict__ U02,
                                           float* __restrict__ U12) {
  int bid = blockIdx.x;
  const float* V; const float* Rt; const float* P; float* U;
  int n1, n2, s, ch, mxg; float inv;
  if (bid < 256)      { V = V01; Rt = R01; P = P1; U = U01; n1 = 256; n2 = 128; s = 2; inv = 1.f / (128.f * 128.f); ch = bid >> 4; mxg = (bid & 15) * 16; }
  else if (bid < 512) { bid -= 256; V = V02; Rt = R02; P = P2; U = U02; n1 = 256; n2 = 64; s = 4; inv = 1.f / (64.f * 64.f); ch = bid >> 4; mxg = (bid & 15) * 16; }
  else                { bid -= 512; V = V12; Rt = R12; P = P2; U = U12; n1 = 128; n2 = 64; s = 2; inv = 1.f / (64.f * 64.f); ch = bid >> 3; mxg = (bid & 7) * 16; }
  __shared__ float Rl[256];
  __shared__ float Vs[16 * 256];
  int t = threadIdx.x;
  for (int i = t; i < n1; i += 256) Rl[i] = Rt[i];
  int myq = t & 63;
  int mxq = t >> 6;  // wave-uniform
  int nmy = n1 >> 6;
  int mask = n1 - 1;
  float acc[4][4];
#pragma unroll
  for (int r = 0; r < 4; ++r)
#pragma unroll
    for (int c = 0; c < 4; ++c) acc[r][c] = 0.f;
  const float* vch = V + (size_t)ch * n2 * n1;
  for (int nx0 = 0; nx0 < n2; nx0 += 16) {
    __syncthreads();
    for (int i = t; i < 16 * n1; i += 256) Vs[i] = vch[(size_t)nx0 * n1 + i];
    __syncthreads();
#pragma unroll
    for (int k = 0; k < 16; ++k) {
      int nx = nx0 + k;
      float rv[4];
#pragma unroll
      for (int r = 0; r < 4; ++r) rv[r] = Rl[(mxg + 4 * mxq + r - s * nx) & mask];
#pragma unroll
      for (int c = 0; c < 4; ++c) {
        float vv = Vs[k * n1 + myq + 64 * c];
#pragma unroll
        for (int r = 0; r < 4; ++r) acc[r][c] += rv[r] * vv;
      }
    }
  }
  float Pv = P[ch];
  float a = PI_F / (float)s;
  int per = 2 * s;
  float smy[4];
  for (int c = 0; c < nmy; ++c) smy[c] = sinf(a * (float)((myq + 64 * c) & (per - 1)));
  float* uch = U + (size_t)ch * n1 * n1;
  for (int r = 0; r < 4; ++r) {
    int mx = mxg + 4 * mxq + r;
    float smx = sinf(a * (float)(mx & (per - 1)));
    for (int c = 0; c < nmy; ++c) {
      int my = myq + 64 * c;
      uch[(size_t)mx * n1 + my] = acc[r][c] - inv * smx * smy[c] * Pv;
    }
  }
}

// Unified 7-point correlation at fine grid:
// z[p] = sum_m A1[m] * A2[(m - p) mod n1], p = (px,py) in
// {(0,0),(0,1),(0,2),(1,0),(1,1),(2,0),(-1,1)}
// grid 768 = 6 groups x 128 (b,l1,l2). One block per output row of 7. No atomics.
__global__ __launch_bounds__(256) void k_corr(const float* __restrict__ X0,
                                              const float* __restrict__ X1,
                                              const float* __restrict__ X2,
                                              const float* __restrict__ U01,
                                              const float* __restrict__ U02,
                                              const float* __restrict__ U12,
                                              float* __restrict__ out) {
  int bid = blockIdx.x;
  int grp = bid >> 7;
  int loc = bid & 127;
  int b = loc >> 6, l1 = (loc >> 3) & 7, l2 = loc & 7;
  const float* A1b; const float* A2b; int n1, base;
  switch (grp) {
    case 0:  A1b = X0; A2b = X0;  n1 = 256; base = 0;   break;
    case 1:  A1b = X0; A2b = U01; n1 = 256; base = 64;  break;
    case 2:  A1b = X0; A2b = U02; n1 = 256; base = 128; break;
    case 3:  A1b = X1; A2b = X1;  n1 = 128; base = 192; break;
    case 4:  A1b = X1; A2b = U12; n1 = 128; base = 256; break;
    default: A1b = X2; A2b = X2;  n1 = 64;  base = 320; break;
  }
  int lgn1 = (n1 == 256) ? 8 : ((n1 == 128) ? 7 : 6);
  int n1sq = n1 * n1;
  const float* A1 = A1b + (size_t)(b * 8 + l1) * n1sq;
  const float* A2 = A2b + (size_t)(b * 8 + l2) * n1sq;
  int t = threadIdx.x;
  int shift = 8 - lgn1;            // 0,1,2
  int tpr = 1 << shift;            // threads per row
  int row = t >> shift;
  int seg = t & (tpr - 1);
  int cols = n1 >> shift;
  int ty0 = seg * cols;
  int mask = n1 - 1;
  const float* r0 = A2 + (size_t)row * n1;                    // px=0
  const float* r1 = A2 + (size_t)((row - 1) & mask) * n1;     // px=1
  const float* r2 = A2 + (size_t)((row - 2) & mask) * n1;     // px=2
  const float* r3 = A2 + (size_t)((row + 1) & mask) * n1;     // px=-1
  const float* rA = A1 + (size_t)row * n1;
  float acc[7] = {0.f, 0.f, 0.f, 0.f, 0.f, 0.f, 0.f};
  for (int ty = ty0; ty < ty0 + cols; ty += 4) {
    int tym = (ty - 4) & mask;
    float4 xv = *(const float4*)(rA + ty);
    float4 a0 = *(const float4*)(r0 + tym);
    float4 b0 = *(const float4*)(r0 + ty);
    float4 a1 = *(const float4*)(r1 + tym);
    float4 b1 = *(const float4*)(r1 + ty);
    float4 b2 = *(const float4*)(r2 + ty);
    float4 a3 = *(const float4*)(r3 + tym);
    float4 b3 = *(const float4*)(r3 + ty);
    // py=0 -> col c; py=1 -> col c-1; py=2 -> col c-2 (window [ty-4, ty+4))
    acc[0] += xv.x * b0.x + xv.y * b0.y + xv.z * b0.z + xv.w * b0.w;  // (0,0)
    acc[1] += xv.x * a0.w + xv.y * b0.x + xv.z * b0.y + xv.w * b0.z;  // (0,1)
    acc[2] += xv.x * a0.z + xv.y * a0.w + xv.z * b0.x + xv.w * b0.y;  // (0,2)
    acc[3] += xv.x * b1.x + xv.y * b1.y + xv.z * b1.z + xv.w * b1.w;  // (1,0)
    acc[4] += xv.x * a1.w + xv.y * b1.x + xv.z * b1.y + xv.w * b1.z;  // (1,1)
    acc[5] += xv.x * b2.x + xv.y * b2.y + xv.z * b2.z + xv.w * b2.w;  // (2,0)
    acc[6] += xv.x * a3.w + xv.y * b3.x + xv.z * b3.y + xv.w * b3.z;  // (-1,1)
  }
  __shared__ float red[4][7];
  int lane = t & 63;
  int wv = t >> 6;
#pragma unroll
  for (int p = 0; p < 7; ++p) {
    float v = acc[p];
#pragma unroll
    for (int off = 32; off > 0; off >>= 1) v += __shfl_down(v, off, 64);
    if (lane == 0) red[wv][p] = v;
  }
  __syncthreads();
  if (t < 7) {
    float v = red[0][t] + red[1][t] + red[2][t] + red[3][t];
    out[((size_t)b * 384 + base + l1 * 8 + l2) * 7 + t] = v;
  }
}

extern "C" void kernel_launch(void* const* d_in, const int* in_sizes, int n_in,
                              void* d_out, int out_size, void* d_ws, size_t ws_size,
                              hipStream_t stream) {
  const float* X0 = (const float*)d_in[0];  // [2,8,256,256]
  const float* X1 = (const float*)d_in[1];  // [2,8,128,128]
  const float* X2 = (const float*)d_in[2];  // [2,8,64,64]
  float* out = (float*)d_out;               // [2,384,7]
  float* ws = (float*)d_ws;

  float* U01 = ws;
  float* U02 = ws + 1048576;
  float* U12 = ws + 2097152;
  float* V01 = ws + 2359296;
  float* V02 = ws + 2883584;
  float* V12 = ws + 3145728;
  float* R01 = ws + 3276800;
  float* R02 = ws + 3277056;
  float* R12 = ws + 3277312;
  float* P1  = ws + 3277440;
  float* P2  = ws + 3277456;

  k_prep<<<33, 256, 0, stream>>>(X1, X2, R01, R02, R12, P1, P2);
  k_V<<<256, 256, 0, stream>>>(X1, X2, R01, R02, R12, V01, V02, V12);
  k_U<<<640, 256, 0, stream>>>(V01, V02, V12, R01, R02, R12, P1, P2,
                               U01, U02, U12);
  k_corr<<<768, 256, 0, stream>>>(X0, X1, X2, U01, U02, U12, out);
}

// Round 4
// 166.669 us; speedup vs baseline: 1.6053x; 1.6053x over previous
//
#include <hip/hip_runtime.h>

#define PI_D 3.14159265358979323846
#define PI_F 3.14159265358979323846f

// ---- workspace layout (floats) ----
// U01 @ 0        : 16*256*256 = 1048576
// U02 @ 1048576  : 1048576
// U12 @ 2097152  : 16*128*128 = 262144
// V01 @ 2359296  : 16*128*256 = 524288
// V02 @ 2883584  : 16*64*256  = 262144
// V12 @ 3145728  : 16*64*128  = 131072
// R01 @ 3276800  : 256
// R02 @ 3277056  : 256
// R12 @ 3277312  : 128
// P1  @ 3277440  : 16
// P2  @ 3277456  : 16     -> ~12.5 MB

__device__ inline float rtab_val(int n, int m2, int t) {
  if (t == 0) return 1.0f;
  double th = PI_D * (double)t / (double)n;
  double v = sin(th * (double)(m2 - 1)) / sin(th) + cos(th * (double)m2);
  return (float)(v / (double)m2);  // 1/m2 per axis
}

// block 0: R tables; blocks 1..16: P1 from X1; blocks 17..32: P2 from X2
__global__ __launch_bounds__(256) void k_prep(const float* __restrict__ X1,
                                              const float* __restrict__ X2,
                                              float* __restrict__ R01,
                                              float* __restrict__ R02,
                                              float* __restrict__ R12,
                                              float* __restrict__ P1,
                                              float* __restrict__ P2) {
  int bid = blockIdx.x;
  int t = threadIdx.x;
  if (bid == 0) {
    R01[t] = rtab_val(256, 128, t);
    R02[t] = rtab_val(256, 64, t);
    if (t < 128) R12[t] = rtab_val(128, 64, t);
    return;
  }
  const float* X; float* P; int lg, ch;
  if (bid <= 16) { X = X1; P = P1; lg = 7; ch = bid - 1; }
  else           { X = X2; P = P2; lg = 6; ch = bid - 17; }
  int n = 1 << lg;
  int total = n * n;
  const float* x = X + (size_t)ch * total;
  float s = 0.f;
  for (int idx = t; idx < total; idx += 256) {
    float v = x[idx];
    s += (((idx >> lg) ^ idx) & 1) ? -v : v;  // (-1)^(nx+ny)
  }
#pragma unroll
  for (int off = 32; off > 0; off >>= 1) s += __shfl_down(s, off, 64);
  __shared__ float red[4];
  if ((t & 63) == 0) red[t >> 6] = s;
  __syncthreads();
  if (t == 0) P[ch] = red[0] + red[1] + red[2] + red[3];
}

// Pass V: v[ch][nx][my] = sum_ny x2[ch][nx][ny] * R[(my - s*ny) mod n1]
// grid 256: [0,128) p01, [128,192) p02, [192,256) p12
__global__ __launch_bounds__(256) void k_V(const float* __restrict__ X1c,
                                           const float* __restrict__ X2c,
                                           const float* __restrict__ R01,
                                           const float* __restrict__ R02,
                                           const float* __restrict__ R12,
                                           float* __restrict__ V01,
                                           float* __restrict__ V02,
                                           float* __restrict__ V12) {
  int bid = blockIdx.x;
  const float* X; const float* Rt; float* V;
  int n1, n2, s, ch, nxg;
  if (bid < 128)      { X = X1c; Rt = R01; V = V01; n1 = 256; n2 = 128; s = 2; ch = bid >> 3; nxg = (bid & 7) * 16; }
  else if (bid < 192) { bid -= 128; X = X2c; Rt = R02; V = V02; n1 = 256; n2 = 64; s = 4; ch = bid >> 2; nxg = (bid & 3) * 16; }
  else                { bid -= 192; X = X2c; Rt = R12; V = V12; n1 = 128; n2 = 64; s = 2; ch = bid >> 2; nxg = (bid & 3) * 16; }
  __shared__ float Rl[256];
  __shared__ float Xs[16 * 128];
  int t = threadIdx.x;
  for (int i = t; i < n1; i += 256) Rl[i] = Rt[i];
  const float* xch = X + (size_t)ch * n2 * n2 + (size_t)nxg * n2;
  for (int i = t; i < 16 * n2; i += 256) Xs[i] = xch[i];
  __syncthreads();
  int myq = t & 63;
  int nxq = t >> 6;  // wave-uniform
  int nmy = n1 >> 6; // 4 or 2
  int mask = n1 - 1;
  float acc[4][4];
#pragma unroll
  for (int r = 0; r < 4; ++r)
#pragma unroll
    for (int c = 0; c < 4; ++c) acc[r][c] = 0.f;
  for (int ny = 0; ny < n2; ++ny) {
    float xv[4];
#pragma unroll
    for (int r = 0; r < 4; ++r) xv[r] = Xs[(4 * nxq + r) * n2 + ny];
#pragma unroll
    for (int c = 0; c < 4; ++c) {
      float rv = Rl[(myq + 64 * c - s * ny) & mask];
#pragma unroll
      for (int r = 0; r < 4; ++r) acc[r][c] += xv[r] * rv;
    }
  }
  float* vch = V + (size_t)ch * n2 * n1;
#pragma unroll
  for (int r = 0; r < 4; ++r)
    for (int c = 0; c < nmy; ++c)
      vch[(size_t)(nxg + 4 * nxq + r) * n1 + myq + 64 * c] = acc[r][c];
}

// Pass U: u[ch][mx][my] = sum_nx R[(mx - s*nx) mod n1] * v[ch][nx][my]
//                         - inv*sin(a*mx)*sin(a*my)*P[ch]
// grid 640: [0,256) p01, [256,512) p02, [512,640) p12
__global__ __launch_bounds__(256) void k_U(const float* __restrict__ V01,
                                           const float* __restrict__ V02,
                                           const float* __restrict__ V12,
                                           const float* __restrict__ R01,
                                           const float* __restrict__ R02,
                                           const float* __restrict__ R12,
                                           const float* __restrict__ P1,
                                           const float* __restrict__ P2,
                                           float* __restrict__ U01,
                                           float* __restrict__ U02,
                                           float* __restrict__ U12) {
  int bid = blockIdx.x;
  const float* V; const float* Rt; const float* P; float* U;
  int n1, n2, s, ch, mxg; float inv;
  if (bid < 256)      { V = V01; Rt = R01; P = P1; U = U01; n1 = 256; n2 = 128; s = 2; inv = 1.f / (128.f * 128.f); ch = bid >> 4; mxg = (bid & 15) * 16; }
  else if (bid < 512) { bid -= 256; V = V02; Rt = R02; P = P2; U = U02; n1 = 256; n2 = 64; s = 4; inv = 1.f / (64.f * 64.f); ch = bid >> 4; mxg = (bid & 15) * 16; }
  else                { bid -= 512; V = V12; Rt = R12; P = P2; U = U12; n1 = 128; n2 = 64; s = 2; inv = 1.f / (64.f * 64.f); ch = bid >> 3; mxg = (bid & 7) * 16; }
  __shared__ float Rl[256];
  __shared__ float Vs[16 * 256];
  int t = threadIdx.x;
  for (int i = t; i < n1; i += 256) Rl[i] = Rt[i];
  int myq = t & 63;
  int mxq = t >> 6;  // wave-uniform
  int nmy = n1 >> 6;
  int mask = n1 - 1;
  float acc[4][4];
#pragma unroll
  for (int r = 0; r < 4; ++r)
#pragma unroll
    for (int c = 0; c < 4; ++c) acc[r][c] = 0.f;
  const float* vch = V + (size_t)ch * n2 * n1;
  for (int nx0 = 0; nx0 < n2; nx0 += 16) {
    __syncthreads();
    for (int i = t; i < 16 * n1; i += 256) Vs[i] = vch[(size_t)nx0 * n1 + i];
    __syncthreads();
#pragma unroll
    for (int k = 0; k < 16; ++k) {
      int nx = nx0 + k;
      float rv[4];
#pragma unroll
      for (int r = 0; r < 4; ++r) rv[r] = Rl[(mxg + 4 * mxq + r - s * nx) & mask];
#pragma unroll
      for (int c = 0; c < 4; ++c) {
        float vv = Vs[k * n1 + myq + 64 * c];
#pragma unroll
        for (int r = 0; r < 4; ++r) acc[r][c] += rv[r] * vv;
      }
    }
  }
  float Pv = P[ch];
  float a = PI_F / (float)s;
  int per = 2 * s;
  float smy[4];
  for (int c = 0; c < nmy; ++c) smy[c] = sinf(a * (float)((myq + 64 * c) & (per - 1)));
  float* uch = U + (size_t)ch * n1 * n1;
  for (int r = 0; r < 4; ++r) {
    int mx = mxg + 4 * mxq + r;
    float smx = sinf(a * (float)(mx & (per - 1)));
    for (int c = 0; c < nmy; ++c) {
      int my = myq + 64 * c;
      uch[(size_t)mx * n1 + my] = acc[r][c] - inv * smx * smy[c] * Pv;
    }
  }
}

// Unified 7-point correlation at fine grid:
// z[p] = sum_m A1[m] * A2[(m - p) mod n1], p = (px,py) in
// {(0,0),(0,1),(0,2),(1,0),(1,1),(2,0),(-1,1)}
// grid 768 = 6 groups x 128 (b,l1,l2). One block per output row of 7.
// Coalesced: tpr = n1/4 lanes per row, lane covers 4 consecutive cols.
__global__ __launch_bounds__(256) void k_corr(const float* __restrict__ X0,
                                              const float* __restrict__ X1,
                                              const float* __restrict__ X2,
                                              const float* __restrict__ U01,
                                              const float* __restrict__ U02,
                                              const float* __restrict__ U12,
                                              float* __restrict__ out) {
  int bid = blockIdx.x;
  int grp = bid >> 7;
  int loc = bid & 127;
  int b = loc >> 6, l1 = (loc >> 3) & 7, l2 = loc & 7;
  const float* A1b; const float* A2b; int n1, base;
  switch (grp) {
    case 0:  A1b = X0; A2b = X0;  n1 = 256; base = 0;   break;
    case 1:  A1b = X0; A2b = U01; n1 = 256; base = 64;  break;
    case 2:  A1b = X0; A2b = U02; n1 = 256; base = 128; break;
    case 3:  A1b = X1; A2b = X1;  n1 = 128; base = 192; break;
    case 4:  A1b = X1; A2b = U12; n1 = 128; base = 256; break;
    default: A1b = X2; A2b = X2;  n1 = 64;  base = 320; break;
  }
  int n1sq = n1 * n1;
  const float* A1 = A1b + (size_t)(b * 8 + l1) * n1sq;
  const float* A2 = A2b + (size_t)(b * 8 + l2) * n1sq;
  int t = threadIdx.x;
  int tpr = n1 >> 2;               // threads per row: 64 / 32 / 16
  int rif = 256 / tpr;             // rows in flight: 4 / 8 / 16
  int rid = t / tpr;               // which in-flight row
  int cid = t & (tpr - 1);
  int ty = cid * 4;
  int tym = (ty - 4) & (n1 - 1);
  int mask = n1 - 1;
  float acc[7] = {0.f, 0.f, 0.f, 0.f, 0.f, 0.f, 0.f};
  for (int row = rid; row < n1; row += rif) {
    const float* rA = A1 + (size_t)row * n1;
    const float* r0 = A2 + (size_t)row * n1;                 // px=0
    const float* r1 = A2 + (size_t)((row - 1) & mask) * n1;  // px=1
    const float* r2 = A2 + (size_t)((row - 2) & mask) * n1;  // px=2
    const float* r3 = A2 + (size_t)((row + 1) & mask) * n1;  // px=-1
    float4 xv = *(const float4*)(rA + ty);
    float4 a0 = *(const float4*)(r0 + tym);
    float4 b0 = *(const float4*)(r0 + ty);
    float4 a1 = *(const float4*)(r1 + tym);
    float4 b1 = *(const float4*)(r1 + ty);
    float4 b2 = *(const float4*)(r2 + ty);
    float4 a3 = *(const float4*)(r3 + tym);
    float4 b3 = *(const float4*)(r3 + ty);
    // py=0 -> col c; py=1 -> col c-1; py=2 -> col c-2
    acc[0] += xv.x * b0.x + xv.y * b0.y + xv.z * b0.z + xv.w * b0.w;  // (0,0)
    acc[1] += xv.x * a0.w + xv.y * b0.x + xv.z * b0.y + xv.w * b0.z;  // (0,1)
    acc[2] += xv.x * a0.z + xv.y * a0.w + xv.z * b0.x + xv.w * b0.y;  // (0,2)
    acc[3] += xv.x * b1.x + xv.y * b1.y + xv.z * b1.z + xv.w * b1.w;  // (1,0)
    acc[4] += xv.x * a1.w + xv.y * b1.x + xv.z * b1.y + xv.w * b1.z;  // (1,1)
    acc[5] += xv.x * b2.x + xv.y * b2.y + xv.z * b2.z + xv.w * b2.w;  // (2,0)
    acc[6] += xv.x * a3.w + xv.y * b3.x + xv.z * b3.y + xv.w * b3.z;  // (-1,1)
  }
  __shared__ float red[4][7];
  int lane = t & 63;
  int wv = t >> 6;
#pragma unroll
  for (int p = 0; p < 7; ++p) {
    float v = acc[p];
#pragma unroll
    for (int off = 32; off > 0; off >>= 1) v += __shfl_down(v, off, 64);
    if (lane == 0) red[wv][p] = v;
  }
  __syncthreads();
  if (t < 7) {
    float v = red[0][t] + red[1][t] + red[2][t] + red[3][t];
    out[((size_t)b * 384 + base + l1 * 8 + l2) * 7 + t] = v;
  }
}

extern "C" void kernel_launch(void* const* d_in, const int* in_sizes, int n_in,
                              void* d_out, int out_size, void* d_ws, size_t ws_size,
                              hipStream_t stream) {
  const float* X0 = (const float*)d_in[0];  // [2,8,256,256]
  const float* X1 = (const float*)d_in[1];  // [2,8,128,128]
  const float* X2 = (const float*)d_in[2];  // [2,8,64,64]
  float* out = (float*)d_out;               // [2,384,7]
  float* ws = (float*)d_ws;

  float* U01 = ws;
  float* U02 = ws + 1048576;
  float* U12 = ws + 2097152;
  float* V01 = ws + 2359296;
  float* V02 = ws + 2883584;
  float* V12 = ws + 3145728;
  float* R01 = ws + 3276800;
  float* R02 = ws + 3277056;
  float* R12 = ws + 3277312;
  float* P1  = ws + 3277440;
  float* P2  = ws + 3277456;

  k_prep<<<33, 256, 0, stream>>>(X1, X2, R01, R02, R12, P1, P2);
  k_V<<<256, 256, 0, stream>>>(X1, X2, R01, R02, R12, V01, V02, V12);
  k_U<<<640, 256, 0, stream>>>(V01, V02, V12, R01, R02, R12, P1, P2,
                               U01, U02, U12);
  k_corr<<<768, 256, 0, stream>>>(X0, X1, X2, U01, U02, U12, out);
}

// Round 5
// 144.806 us; speedup vs baseline: 1.8477x; 1.1510x over previous
//
#include <hip/hip_runtime.h>

#define PI_D 3.14159265358979323846
#define PI_F 3.14159265358979323846f

// ---- workspace layout (floats) ----
// U01 @ 0        : 16*256*256 = 1048576
// U02 @ 1048576  : 1048576
// U12 @ 2097152  : 16*128*128 = 262144
// V01 @ 2359296  : 16*128*256 = 524288
// V02 @ 2883584  : 16*64*256  = 262144
// V12 @ 3145728  : 16*64*128  = 131072
// R01 @ 3276800  : 256
// R02 @ 3277056  : 256
// R12 @ 3277312  : 128
// P1p @ 3277440  : 128 (16ch x 8 splits)
// P2p @ 3277568  : 64  (16ch x 4 splits)

__device__ inline float rtab_val(int n, int m2, int t) {
  if (t == 0) return 1.0f;
  double th = PI_D * (double)t / (double)n;
  double v = sin(th * (double)(m2 - 1)) / sin(th) + cos(th * (double)m2);
  return (float)(v / (double)m2);  // 1/m2 per axis
}

// block 0: R tables; blocks 1..128: P1 partials (16ch x 8); 129..192: P2 (16ch x 4)
__global__ __launch_bounds__(256) void k_prep(const float* __restrict__ X1,
                                              const float* __restrict__ X2,
                                              float* __restrict__ R01,
                                              float* __restrict__ R02,
                                              float* __restrict__ R12,
                                              float* __restrict__ P1p,
                                              float* __restrict__ P2p) {
  int bid = blockIdx.x;
  int t = threadIdx.x;
  if (bid == 0) {
    R01[t] = rtab_val(256, 128, t);
    R02[t] = rtab_val(256, 64, t);
    if (t < 128) R12[t] = rtab_val(128, 64, t);
    return;
  }
  const float* X; float* P; int lg, ch, split, nsp;
  if (bid <= 128) { bid -= 1;   X = X1; P = P1p; lg = 7; nsp = 8; }
  else            { bid -= 129; X = X2; P = P2p; lg = 6; nsp = 4; }
  ch = bid / nsp; split = bid % nsp;
  int n = 1 << lg;
  int total = n * n;
  int chunk = total / nsp;
  const float* x = X + (size_t)ch * total + split * chunk;
  float s = 0.f;
  int b0 = split * chunk;
  for (int i = t; i < chunk; i += 256) {
    int idx = b0 + i;
    float v = x[i];
    s += (((idx >> lg) ^ idx) & 1) ? -v : v;  // (-1)^(nx+ny)
  }
#pragma unroll
  for (int off = 32; off > 0; off >>= 1) s += __shfl_down(s, off, 64);
  __shared__ float red[4];
  if ((t & 63) == 0) red[t >> 6] = s;
  __syncthreads();
  if (t == 0) P[ch * nsp + split] = red[0] + red[1] + red[2] + red[3];
}

// Pass V: v[ch][nx][my] = sum_ny x2[ch][nx][ny] * R[(my - s*ny) mod n1]
__global__ __launch_bounds__(256) void k_V(const float* __restrict__ X1c,
                                           const float* __restrict__ X2c,
                                           const float* __restrict__ R01,
                                           const float* __restrict__ R02,
                                           const float* __restrict__ R12,
                                           float* __restrict__ V01,
                                           float* __restrict__ V02,
                                           float* __restrict__ V12) {
  int bid = blockIdx.x;
  const float* X; const float* Rt; float* V;
  int n1, n2, s, ch, nxg;
  if (bid < 128)      { X = X1c; Rt = R01; V = V01; n1 = 256; n2 = 128; s = 2; ch = bid >> 3; nxg = (bid & 7) * 16; }
  else if (bid < 192) { bid -= 128; X = X2c; Rt = R02; V = V02; n1 = 256; n2 = 64; s = 4; ch = bid >> 2; nxg = (bid & 3) * 16; }
  else                { bid -= 192; X = X2c; Rt = R12; V = V12; n1 = 128; n2 = 64; s = 2; ch = bid >> 2; nxg = (bid & 3) * 16; }
  __shared__ float Rl[256];
  __shared__ float Xs[16 * 128];
  int t = threadIdx.x;
  for (int i = t; i < n1; i += 256) Rl[i] = Rt[i];
  const float* xch = X + (size_t)ch * n2 * n2 + (size_t)nxg * n2;
  for (int i = t; i < 16 * n2; i += 256) Xs[i] = xch[i];
  __syncthreads();
  int myq = t & 63;
  int nxq = t >> 6;  // wave-uniform
  int nmy = n1 >> 6; // 4 or 2
  int mask = n1 - 1;
  float acc[4][4];
#pragma unroll
  for (int r = 0; r < 4; ++r)
#pragma unroll
    for (int c = 0; c < 4; ++c) acc[r][c] = 0.f;
  for (int ny = 0; ny < n2; ++ny) {
    float xv[4];
#pragma unroll
    for (int r = 0; r < 4; ++r) xv[r] = Xs[(4 * nxq + r) * n2 + ny];
#pragma unroll
    for (int c = 0; c < 4; ++c) {
      float rv = Rl[(myq + 64 * c - s * ny) & mask];
#pragma unroll
      for (int r = 0; r < 4; ++r) acc[r][c] += xv[r] * rv;
    }
  }
  float* vch = V + (size_t)ch * n2 * n1;
#pragma unroll
  for (int r = 0; r < 4; ++r)
    for (int c = 0; c < nmy; ++c)
      vch[(size_t)(nxg + 4 * nxq + r) * n1 + myq + 64 * c] = acc[r][c];
}

// Pass U: u[ch][mx][my] = sum_nx R[(mx - s*nx) mod n1] * v[ch][nx][my]
//                         - inv*sin(a*mx)*sin(a*my)*P[ch]
__global__ __launch_bounds__(256) void k_U(const float* __restrict__ V01,
                                           const float* __restrict__ V02,
                                           const float* __restrict__ V12,
                                           const float* __restrict__ R01,
                                           const float* __restrict__ R02,
                                           const float* __restrict__ R12,
                                           const float* __restrict__ P1p,
                                           const float* __restrict__ P2p,
                                           float* __restrict__ U01,
                                           float* __restrict__ U02,
                                           float* __restrict__ U12) {
  int bid = blockIdx.x;
  const float* V; const float* Rt; const float* Pp; float* U;
  int n1, n2, s, ch, mxg, nsp; float inv;
  if (bid < 256)      { V = V01; Rt = R01; Pp = P1p; nsp = 8; U = U01; n1 = 256; n2 = 128; s = 2; inv = 1.f / (128.f * 128.f); ch = bid >> 4; mxg = (bid & 15) * 16; }
  else if (bid < 512) { bid -= 256; V = V02; Rt = R02; Pp = P2p; nsp = 4; U = U02; n1 = 256; n2 = 64; s = 4; inv = 1.f / (64.f * 64.f); ch = bid >> 4; mxg = (bid & 15) * 16; }
  else                { bid -= 512; V = V12; Rt = R12; Pp = P2p; nsp = 4; U = U12; n1 = 128; n2 = 64; s = 2; inv = 1.f / (64.f * 64.f); ch = bid >> 3; mxg = (bid & 7) * 16; }
  __shared__ float Rl[256];
  __shared__ float Vs[16 * 256];
  int t = threadIdx.x;
  for (int i = t; i < n1; i += 256) Rl[i] = Rt[i];
  int myq = t & 63;
  int mxq = t >> 6;  // wave-uniform
  int nmy = n1 >> 6;
  int mask = n1 - 1;
  float acc[4][4];
#pragma unroll
  for (int r = 0; r < 4; ++r)
#pragma unroll
    for (int c = 0; c < 4; ++c) acc[r][c] = 0.f;
  const float* vch = V + (size_t)ch * n2 * n1;
  for (int nx0 = 0; nx0 < n2; nx0 += 16) {
    __syncthreads();
    for (int i = t; i < 16 * n1; i += 256) Vs[i] = vch[(size_t)nx0 * n1 + i];
    __syncthreads();
#pragma unroll
    for (int k = 0; k < 16; ++k) {
      int nx = nx0 + k;
      float rv[4];
#pragma unroll
      for (int r = 0; r < 4; ++r) rv[r] = Rl[(mxg + 4 * mxq + r - s * nx) & mask];
#pragma unroll
      for (int c = 0; c < 4; ++c) {
        float vv = Vs[k * n1 + myq + 64 * c];
#pragma unroll
        for (int r = 0; r < 4; ++r) acc[r][c] += rv[r] * vv;
      }
    }
  }
  float Pv = 0.f;
  for (int i = 0; i < nsp; ++i) Pv += Pp[ch * nsp + i];
  float a = PI_F / (float)s;
  int per = 2 * s;
  float smy[4];
  for (int c = 0; c < nmy; ++c) smy[c] = sinf(a * (float)((myq + 64 * c) & (per - 1)));
  float* uch = U + (size_t)ch * n1 * n1;
  for (int r = 0; r < 4; ++r) {
    int mx = mxg + 4 * mxq + r;
    float smx = sinf(a * (float)(mx & (per - 1)));
    for (int c = 0; c < nmy; ++c) {
      int my = myq + 64 * c;
      uch[(size_t)mx * n1 + my] = acc[r][c] - inv * smx * smy[c] * Pv;
    }
  }
}

// 7-point correlation, A2 reused across all 8 l1 channels.
// block = (grp, b, l2, rowchunk of 16). atomicAdd partial sums into zeroed out.
__global__ __launch_bounds__(256) void k_corr(const float* __restrict__ X0,
                                              const float* __restrict__ X1,
                                              const float* __restrict__ X2,
                                              const float* __restrict__ U01,
                                              const float* __restrict__ U02,
                                              const float* __restrict__ U12,
                                              float* __restrict__ out) {
  int bid = blockIdx.x;
  const float* A1b; const float* A2b; int loc, lgn1, base;
  if (bid < 256)       { loc = bid;        A1b = X0; A2b = X0;  lgn1 = 8; base = 0;   }
  else if (bid < 512)  { loc = bid - 256;  A1b = X0; A2b = U01; lgn1 = 8; base = 64;  }
  else if (bid < 768)  { loc = bid - 512;  A1b = X0; A2b = U02; lgn1 = 8; base = 128; }
  else if (bid < 896)  { loc = bid - 768;  A1b = X1; A2b = X1;  lgn1 = 7; base = 192; }
  else if (bid < 1024) { loc = bid - 896;  A1b = X1; A2b = U12; lgn1 = 7; base = 256; }
  else                 { loc = bid - 1024; A1b = X2; A2b = X2;  lgn1 = 6; base = 320; }
  int n1 = 1 << lgn1;
  int lgc = lgn1 - 4;              // log2(#chunks of 16 rows)
  int chunk = loc & ((1 << lgc) - 1);
  int bl2 = loc >> lgc;
  int b = bl2 >> 3, l2 = bl2 & 7;
  int n1sq = n1 * n1;
  int mask = n1 - 1;
  const float* A1 = A1b + (size_t)(b * 8) * n1sq;
  const float* A2 = A2b + (size_t)(b * 8 + l2) * n1sq;
  int t = threadIdx.x;
  int lgtpr = lgn1 - 2;            // threads per row: 64/32/16
  int tpr = 1 << lgtpr;
  int rif = 256 >> lgtpr;          // rows in flight: 4/8/16
  int rid = t >> lgtpr;
  int cid = t & (tpr - 1);
  int ty = cid * 4;
  int tym = (ty - 4) & mask;
  float acc[8][7];
#pragma unroll
  for (int l1 = 0; l1 < 8; ++l1)
#pragma unroll
    for (int p = 0; p < 7; ++p) acc[l1][p] = 0.f;
  for (int rr = 0; rr < 16; rr += rif) {
    int row = chunk * 16 + rr + rid;
    const float* r0 = A2 + (size_t)row * n1;
    const float* r1 = A2 + (size_t)((row - 1) & mask) * n1;
    const float* r2 = A2 + (size_t)((row - 2) & mask) * n1;
    const float* r3 = A2 + (size_t)((row + 1) & mask) * n1;
    float4 a0 = *(const float4*)(r0 + tym);
    float4 b0 = *(const float4*)(r0 + ty);
    float4 a1 = *(const float4*)(r1 + tym);
    float4 b1 = *(const float4*)(r1 + ty);
    float4 b2 = *(const float4*)(r2 + ty);
    float4 a3 = *(const float4*)(r3 + tym);
    float4 b3 = *(const float4*)(r3 + ty);
    const float* rA = A1 + (size_t)row * n1 + ty;
#pragma unroll
    for (int l1 = 0; l1 < 8; ++l1) {
      float4 xv = *(const float4*)(rA + (size_t)l1 * n1sq);
      acc[l1][0] += xv.x * b0.x + xv.y * b0.y + xv.z * b0.z + xv.w * b0.w;  // (0,0)
      acc[l1][1] += xv.x * a0.w + xv.y * b0.x + xv.z * b0.y + xv.w * b0.z;  // (0,1)
      acc[l1][2] += xv.x * a0.z + xv.y * a0.w + xv.z * b0.x + xv.w * b0.y;  // (0,2)
      acc[l1][3] += xv.x * b1.x + xv.y * b1.y + xv.z * b1.z + xv.w * b1.w;  // (1,0)
      acc[l1][4] += xv.x * a1.w + xv.y * b1.x + xv.z * b1.y + xv.w * b1.z;  // (1,1)
      acc[l1][5] += xv.x * b2.x + xv.y * b2.y + xv.z * b2.z + xv.w * b2.w;  // (2,0)
      acc[l1][6] += xv.x * a3.w + xv.y * b3.x + xv.z * b3.y + xv.w * b3.z;  // (-1,1)
    }
  }
  __shared__ float red[4][56];
  int lane = t & 63;
  int wv = t >> 6;
#pragma unroll
  for (int l1 = 0; l1 < 8; ++l1)
#pragma unroll
    for (int p = 0; p < 7; ++p) {
      float v = acc[l1][p];
#pragma unroll
      for (int off = 32; off > 0; off >>= 1) v += __shfl_down(v, off, 64);
      if (lane == 0) red[wv][l1 * 7 + p] = v;
    }
  __syncthreads();
  if (t < 56) {
    float v = red[0][t] + red[1][t] + red[2][t] + red[3][t];
    int l1 = t / 7, p = t % 7;
    atomicAdd(&out[((size_t)b * 384 + base + l1 * 8 + l2) * 7 + p], v);
  }
}

extern "C" void kernel_launch(void* const* d_in, const int* in_sizes, int n_in,
                              void* d_out, int out_size, void* d_ws, size_t ws_size,
                              hipStream_t stream) {
  const float* X0 = (const float*)d_in[0];  // [2,8,256,256]
  const float* X1 = (const float*)d_in[1];  // [2,8,128,128]
  const float* X2 = (const float*)d_in[2];  // [2,8,64,64]
  float* out = (float*)d_out;               // [2,384,7]
  float* ws = (float*)d_ws;

  float* U01 = ws;
  float* U02 = ws + 1048576;
  float* U12 = ws + 2097152;
  float* V01 = ws + 2359296;
  float* V02 = ws + 2883584;
  float* V12 = ws + 3145728;
  float* R01 = ws + 3276800;
  float* R02 = ws + 3277056;
  float* R12 = ws + 3277312;
  float* P1p = ws + 3277440;
  float* P2p = ws + 3277568;

  k_prep<<<193, 256, 0, stream>>>(X1, X2, R01, R02, R12, P1p, P2p);
  k_V<<<256, 256, 0, stream>>>(X1, X2, R01, R02, R12, V01, V02, V12);
  k_U<<<640, 256, 0, stream>>>(V01, V02, V12, R01, R02, R12, P1p, P2p,
                               U01, U02, U12);
  hipMemsetAsync(d_out, 0, (size_t)out_size * sizeof(float), stream);
  k_corr<<<1088, 256, 0, stream>>>(X0, X1, X2, U01, U02, U12, out);
}

// Round 6
// 129.367 us; speedup vs baseline: 2.0682x; 1.1193x over previous
//
#include <hip/hip_runtime.h>

#define PI_D 3.14159265358979323846
#define PI_F 3.14159265358979323846f

// ---- workspace layout (floats) ----
// U01 @ 0        : 16*256*256 = 1048576
// U02 @ 1048576  : 1048576
// U12 @ 2097152  : 16*128*128 = 262144
// V01 @ 2359296  : 16*128*256 = 524288
// V02 @ 2883584  : 16*64*256  = 262144
// V12 @ 3145728  : 16*64*128  = 131072
// P1p @ 3276800  : 128 (16ch x 8 splits)
// P2p @ 3276928  : 64  (16ch x 4 splits)

// Band-limit (spectral upsample) kernel value; m2 == coarse size n2.
__device__ inline float rtab_val(int n, int m2, int t) {
  if (t == 0) return 1.0f;
  double th = PI_D * (double)t / (double)n;
  double v = sin(th * (double)(m2 - 1)) / sin(th) + cos(th * (double)m2);
  return (float)(v / (double)m2);  // 1/m2 per axis
}

// Fused front kernel:
// bid 0..127   : P1 partials (X1, 16ch x 8 splits)
// bid 128..191 : P2 partials (X2, 16ch x 4 splits)
// bid 192..447 : V pass (local R table per block)
// bid 448      : zero d_out
__global__ __launch_bounds__(256) void k_front(const float* __restrict__ X1,
                                               const float* __restrict__ X2,
                                               float* __restrict__ P1p,
                                               float* __restrict__ P2p,
                                               float* __restrict__ V01,
                                               float* __restrict__ V02,
                                               float* __restrict__ V12,
                                               float* __restrict__ out) {
  int bid = blockIdx.x;
  int t = threadIdx.x;
  if (bid == 448) {
    for (int i = t; i < 5376; i += 256) out[i] = 0.f;
    return;
  }
  if (bid < 192) {
    // alternating-sign projections P = sum x * (-1)^(nx+ny), split partials
    const float* X; float* P; int lg, nsp, idx0;
    if (bid < 128) { X = X1; P = P1p; lg = 7; nsp = 8; idx0 = bid; }
    else           { X = X2; P = P2p; lg = 6; nsp = 4; idx0 = bid - 128; }
    int ch = idx0 / nsp, split = idx0 % nsp;
    int n = 1 << lg;
    int total = n * n;
    int chunk = total / nsp;
    int b0 = split * chunk;
    const float* x = X + (size_t)ch * total + b0;
    float s = 0.f;
    for (int i = t; i < chunk; i += 256) {
      int idx = b0 + i;
      float v = x[i];
      s += (((idx >> lg) ^ idx) & 1) ? -v : v;
    }
#pragma unroll
    for (int off = 32; off > 0; off >>= 1) s += __shfl_down(s, off, 64);
    __shared__ float red[4];
    if ((t & 63) == 0) red[t >> 6] = s;
    __syncthreads();
    if (t == 0) P[ch * nsp + split] = red[0] + red[1] + red[2] + red[3];
    return;
  }
  // ---- V pass: v[ch][nx][my] = sum_ny x2[ch][nx][ny] * R[(my - s*ny) mod n1]
  int vbid = bid - 192;
  const float* X; float* V;
  int n1, n2, s, ch, nxg;
  if (vbid < 128)      { X = X1; V = V01; n1 = 256; n2 = 128; s = 2; ch = vbid >> 3; nxg = (vbid & 7) * 16; }
  else if (vbid < 192) { vbid -= 128; X = X2; V = V02; n1 = 256; n2 = 64; s = 4; ch = vbid >> 2; nxg = (vbid & 3) * 16; }
  else                 { vbid -= 192; X = X2; V = V12; n1 = 128; n2 = 64; s = 2; ch = vbid >> 2; nxg = (vbid & 3) * 16; }
  __shared__ float Rl[256];
  __shared__ float Xs[16 * 128];
  for (int i = t; i < n1; i += 256) Rl[i] = rtab_val(n1, n2, i);
  const float4* xch4 =
      (const float4*)(X + (size_t)ch * n2 * n2 + (size_t)nxg * n2);
  int nx4 = (16 * n2) >> 2;
  for (int i = t; i < nx4; i += 256) ((float4*)Xs)[i] = xch4[i];
  __syncthreads();
  int myq = t & 63;
  int nxq = t >> 6;  // wave-uniform
  int nmy = n1 >> 6; // 4 or 2
  int mask = n1 - 1;
  float acc[4][4];
#pragma unroll
  for (int r = 0; r < 4; ++r)
#pragma unroll
    for (int c = 0; c < 4; ++c) acc[r][c] = 0.f;
  for (int ny = 0; ny < n2; ++ny) {
    float xv[4];
#pragma unroll
    for (int r = 0; r < 4; ++r) xv[r] = Xs[(4 * nxq + r) * n2 + ny];
#pragma unroll
    for (int c = 0; c < 4; ++c) {
      float rv = Rl[(myq + 64 * c - s * ny) & mask];
#pragma unroll
      for (int r = 0; r < 4; ++r) acc[r][c] += xv[r] * rv;
    }
  }
  float* vch = V + (size_t)ch * n2 * n1;
#pragma unroll
  for (int r = 0; r < 4; ++r)
    for (int c = 0; c < nmy; ++c)
      vch[(size_t)(nxg + 4 * nxq + r) * n1 + myq + 64 * c] = acc[r][c];
}

// Pass U: u[ch][mx][my] = sum_nx R[(mx - s*nx) mod n1] * v[ch][nx][my]
//                         - inv*sin(a*mx)*sin(a*my)*P[ch]
__global__ __launch_bounds__(256) void k_U(const float* __restrict__ V01,
                                           const float* __restrict__ V02,
                                           const float* __restrict__ V12,
                                           const float* __restrict__ P1p,
                                           const float* __restrict__ P2p,
                                           float* __restrict__ U01,
                                           float* __restrict__ U02,
                                           float* __restrict__ U12) {
  int bid = blockIdx.x;
  const float* V; const float* Pp; float* U;
  int n1, n2, s, ch, mxg, nsp; float inv;
  if (bid < 256)      { V = V01; Pp = P1p; nsp = 8; U = U01; n1 = 256; n2 = 128; s = 2; inv = 1.f / (128.f * 128.f); ch = bid >> 4; mxg = (bid & 15) * 16; }
  else if (bid < 512) { bid -= 256; V = V02; Pp = P2p; nsp = 4; U = U02; n1 = 256; n2 = 64; s = 4; inv = 1.f / (64.f * 64.f); ch = bid >> 4; mxg = (bid & 15) * 16; }
  else                { bid -= 512; V = V12; Pp = P2p; nsp = 4; U = U12; n1 = 128; n2 = 64; s = 2; inv = 1.f / (64.f * 64.f); ch = bid >> 3; mxg = (bid & 7) * 16; }
  __shared__ float Rl[256];
  __shared__ float Vs[16 * 256];
  int t = threadIdx.x;
  for (int i = t; i < n1; i += 256) Rl[i] = rtab_val(n1, n2, i);
  int myq = t & 63;
  int mxq = t >> 6;  // wave-uniform
  int nmy = n1 >> 6;
  int mask = n1 - 1;
  float acc[4][4];
#pragma unroll
  for (int r = 0; r < 4; ++r)
#pragma unroll
    for (int c = 0; c < 4; ++c) acc[r][c] = 0.f;
  const float* vch = V + (size_t)ch * n2 * n1;
  int nv4 = (16 * n1) >> 2;
  for (int nx0 = 0; nx0 < n2; nx0 += 16) {
    __syncthreads();
    const float4* src4 = (const float4*)(vch + (size_t)nx0 * n1);
    for (int i = t; i < nv4; i += 256) ((float4*)Vs)[i] = src4[i];
    __syncthreads();
#pragma unroll
    for (int k = 0; k < 16; ++k) {
      int nx = nx0 + k;
      float rv[4];
#pragma unroll
      for (int r = 0; r < 4; ++r) rv[r] = Rl[(mxg + 4 * mxq + r - s * nx) & mask];
#pragma unroll
      for (int c = 0; c < 4; ++c) {
        float vv = Vs[k * n1 + myq + 64 * c];
#pragma unroll
        for (int r = 0; r < 4; ++r) acc[r][c] += rv[r] * vv;
      }
    }
  }
  float Pv = 0.f;
  for (int i = 0; i < nsp; ++i) Pv += Pp[ch * nsp + i];
  float a = PI_F / (float)s;
  int per = 2 * s;
  float smy[4];
  for (int c = 0; c < nmy; ++c) smy[c] = sinf(a * (float)((myq + 64 * c) & (per - 1)));
  float* uch = U + (size_t)ch * n1 * n1;
  for (int r = 0; r < 4; ++r) {
    int mx = mxg + 4 * mxq + r;
    float smx = sinf(a * (float)(mx & (per - 1)));
    for (int c = 0; c < nmy; ++c) {
      int my = myq + 64 * c;
      uch[(size_t)mx * n1 + my] = acc[r][c] - inv * smx * smy[c] * Pv;
    }
  }
}

// 7-point correlation, A2 reused across all 8 l1 channels.
// block = (grp, b, l2, rowchunk of 16). atomicAdd partial sums into zeroed out.
__global__ __launch_bounds__(256) void k_corr(const float* __restrict__ X0,
                                              const float* __restrict__ X1,
                                              const float* __restrict__ X2,
                                              const float* __restrict__ U01,
                                              const float* __restrict__ U02,
                                              const float* __restrict__ U12,
                                              float* __restrict__ out) {
  int bid = blockIdx.x;
  const float* A1b; const float* A2b; int loc, lgn1, base;
  if (bid < 256)       { loc = bid;        A1b = X0; A2b = X0;  lgn1 = 8; base = 0;   }
  else if (bid < 512)  { loc = bid - 256;  A1b = X0; A2b = U01; lgn1 = 8; base = 64;  }
  else if (bid < 768)  { loc = bid - 512;  A1b = X0; A2b = U02; lgn1 = 8; base = 128; }
  else if (bid < 896)  { loc = bid - 768;  A1b = X1; A2b = X1;  lgn1 = 7; base = 192; }
  else if (bid < 1024) { loc = bid - 896;  A1b = X1; A2b = U12; lgn1 = 7; base = 256; }
  else                 { loc = bid - 1024; A1b = X2; A2b = X2;  lgn1 = 6; base = 320; }
  int n1 = 1 << lgn1;
  int lgc = lgn1 - 4;              // log2(#chunks of 16 rows)
  int chunk = loc & ((1 << lgc) - 1);
  int bl2 = loc >> lgc;
  int b = bl2 >> 3, l2 = bl2 & 7;
  int n1sq = n1 * n1;
  int mask = n1 - 1;
  const float* A1 = A1b + (size_t)(b * 8) * n1sq;
  const float* A2 = A2b + (size_t)(b * 8 + l2) * n1sq;
  int t = threadIdx.x;
  int lgtpr = lgn1 - 2;            // threads per row: 64/32/16
  int tpr = 1 << lgtpr;
  int rif = 256 >> lgtpr;          // rows in flight: 4/8/16
  int rid = t >> lgtpr;
  int cid = t & (tpr - 1);
  int ty = cid * 4;
  int tym = (ty - 4) & mask;
  float acc[8][7];
#pragma unroll
  for (int l1 = 0; l1 < 8; ++l1)
#pragma unroll
    for (int p = 0; p < 7; ++p) acc[l1][p] = 0.f;
  for (int rr = 0; rr < 16; rr += rif) {
    int row = chunk * 16 + rr + rid;
    const float* r0 = A2 + (size_t)row * n1;
    const float* r1 = A2 + (size_t)((row - 1) & mask) * n1;
    const float* r2 = A2 + (size_t)((row - 2) & mask) * n1;
    const float* r3 = A2 + (size_t)((row + 1) & mask) * n1;
    float4 a0 = *(const float4*)(r0 + tym);
    float4 b0 = *(const float4*)(r0 + ty);
    float4 a1 = *(const float4*)(r1 + tym);
    float4 b1 = *(const float4*)(r1 + ty);
    float4 b2 = *(const float4*)(r2 + ty);
    float4 a3 = *(const float4*)(r3 + tym);
    float4 b3 = *(const float4*)(r3 + ty);
    const float* rA = A1 + (size_t)row * n1 + ty;
#pragma unroll
    for (int l1 = 0; l1 < 8; ++l1) {
      float4 xv = *(const float4*)(rA + (size_t)l1 * n1sq);
      acc[l1][0] += xv.x * b0.x + xv.y * b0.y + xv.z * b0.z + xv.w * b0.w;  // (0,0)
      acc[l1][1] += xv.x * a0.w + xv.y * b0.x + xv.z * b0.y + xv.w * b0.z;  // (0,1)
      acc[l1][2] += xv.x * a0.z + xv.y * a0.w + xv.z * b0.x + xv.w * b0.y;  // (0,2)
      acc[l1][3] += xv.x * b1.x + xv.y * b1.y + xv.z * b1.z + xv.w * b1.w;  // (1,0)
      acc[l1][4] += xv.x * a1.w + xv.y * b1.x + xv.z * b1.y + xv.w * b1.z;  // (1,1)
      acc[l1][5] += xv.x * b2.x + xv.y * b2.y + xv.z * b2.z + xv.w * b2.w;  // (2,0)
      acc[l1][6] += xv.x * a3.w + xv.y * b3.x + xv.z * b3.y + xv.w * b3.z;  // (-1,1)
    }
  }
  __shared__ float red[4][56];
  int lane = t & 63;
  int wv = t >> 6;
#pragma unroll
  for (int l1 = 0; l1 < 8; ++l1)
#pragma unroll
    for (int p = 0; p < 7; ++p) {
      float v = acc[l1][p];
#pragma unroll
      for (int off = 32; off > 0; off >>= 1) v += __shfl_down(v, off, 64);
      if (lane == 0) red[wv][l1 * 7 + p] = v;
    }
  __syncthreads();
  if (t < 56) {
    float v = red[0][t] + red[1][t] + red[2][t] + red[3][t];
    int l1 = t / 7, p = t % 7;
    atomicAdd(&out[((size_t)b * 384 + base + l1 * 8 + l2) * 7 + p], v);
  }
}

extern "C" void kernel_launch(void* const* d_in, const int* in_sizes, int n_in,
                              void* d_out, int out_size, void* d_ws, size_t ws_size,
                              hipStream_t stream) {
  const float* X0 = (const float*)d_in[0];  // [2,8,256,256]
  const float* X1 = (const float*)d_in[1];  // [2,8,128,128]
  const float* X2 = (const float*)d_in[2];  // [2,8,64,64]
  float* out = (float*)d_out;               // [2,384,7]
  float* ws = (float*)d_ws;

  float* U01 = ws;
  float* U02 = ws + 1048576;
  float* U12 = ws + 2097152;
  float* V01 = ws + 2359296;
  float* V02 = ws + 2883584;
  float* V12 = ws + 3145728;
  float* P1p = ws + 3276800;
  float* P2p = ws + 3276928;

  k_front<<<449, 256, 0, stream>>>(X1, X2, P1p, P2p, V01, V02, V12, out);
  k_U<<<640, 256, 0, stream>>>(V01, V02, V12, P1p, P2p, U01, U02, U12);
  k_corr<<<1088, 256, 0, stream>>>(X0, X1, X2, U01, U02, U12, out);
}